// Round 18
// baseline (99.502 us; speedup 1.0000x reference)
//
#include <hip/hip_runtime.h>
#include <cstddef>
#include <cstdint>

// Problem constants
#define Bb   32
#define Ss   512
#define Dd   768
#define Ww   256
#define Pp   1024
#define NH   300            // hidden
#define SLOT1 320           // slot-1 column base (128B-aligned)
#define NPAD 640            // padded proj row: [0,300) slot0, [320,620) slot1
#define Mm   (Bb * Ww)      // 8192 words
#define ZROW 8192           // zero row index in each proj buffer
#define ZOFF (ZROW * NPAD)  // element offset of zero row
#define PBUF ((Mm + 1) * NPAD)   // elements per proj partial buffer (8193 rows)
#define KH   384            // K half
#define NST  12             // K-steps per wave (KH/32)

typedef __attribute__((ext_vector_type(8))) short bf16x8;
typedef __attribute__((ext_vector_type(4))) float f32x4;

#define GPTR(p) ((const __attribute__((address_space(1))) void*)(p))
#define LPTR(p) ((__attribute__((address_space(3))) void*)(p))

__device__ __forceinline__ unsigned short f2bf(float x) {
    unsigned u = __builtin_bit_cast(unsigned, x);
    u += 0x7fffu + ((u >> 16) & 1u);          // RNE
    return (unsigned short)(u >> 16);
}
__device__ __forceinline__ float bf2f(unsigned short u) {
    return __builtin_bit_cast(float, (unsigned)u << 16);
}
__device__ __forceinline__ float fast_tanh(float x) {
    x = fminf(fmaxf(x, -15.0f), 15.0f);
    float e = __expf(2.0f * x);
    return 1.0f - 2.0f * __builtin_amdgcn_rcpf(e + 1.0f);
}

// -------------------------------------------------------------------------
// Kernel 1 (prep), grid-stride 1024x256 (R17-identical):
//   (a) mean-pool h -> emb bf16  (b) repack w1 -> BmatT  (c) zero rows
// -------------------------------------------------------------------------
__global__ __launch_bounds__(256) void prep_kernel(
    const float* __restrict__ h, const float* __restrict__ w1,
    const int* __restrict__ word_start, const int* __restrict__ word_len,
    unsigned short* __restrict__ emb, unsigned short* __restrict__ bmatT,
    unsigned short* __restrict__ proj)
{
    const int gid    = blockIdx.x * 256 + threadIdx.x;
    const int stride = 1024 * 256;

    for (int u = gid; u < Mm * 192; u += stride) {
        const int m = u / 192;
        const int c = u - m * 192;
        const int b   = m >> 8;
        const int s0  = word_start[m];
        const int len = word_len[m];
        const float* p = h + (size_t)b * (Ss * Dd) + (size_t)s0 * Dd + c * 4;
        float4 v = *(const float4*)p;
        if (len == 2) {
            float4 v2 = *(const float4*)(p + Dd);
            v.x = (v.x + v2.x) * 0.5f;
            v.y = (v.y + v2.y) * 0.5f;
            v.z = (v.z + v2.z) * 0.5f;
            v.w = (v.w + v2.w) * 0.5f;
        }
        ushort4 o = make_ushort4(f2bf(v.x), f2bf(v.y), f2bf(v.z), f2bf(v.w));
        *(ushort4*)(emb + (size_t)m * Dd + c * 4) = o;
    }

    for (int u = gid; u < Dd * NPAD; u += stride) {
        const int k = u / NPAD;
        const int n = u - k * NPAD;
        float v = 0.0f;
        if (n < NH)                            v = w1[(size_t)k * NH + n];
        else if (n >= SLOT1 && n < SLOT1 + NH) v = w1[(size_t)(Dd + k) * NH + (n - SLOT1)];
        bmatT[(size_t)n * Dd + k] = f2bf(v);
    }

    if (gid < NPAD / 4) {
        *(ushort4*)(proj + ZOFF + gid * 4)        = make_ushort4(0, 0, 0, 0);
        *(ushort4*)(proj + PBUF + ZOFF + gid * 4) = make_ushort4(0, 0, 0, 0);
    }
}

// -------------------------------------------------------------------------
// Kernel 2: BARRIER-FREE single-wave MFMA GEMM, K-SPLIT x2:
//   proj[kh] = emb[:, kh*384:+384] @ Bmat[kh*384:+384, :]
// 2560 blocks x 64 threads = 1 wave/block, 64x64 tile (4x4 frags), BK=32,
// 12 K-steps. Private 16 KB LDS (2-buf A 4KB + B 4KB each): exactly 10
// blocks/CU. NO s_barrier anywhere: each wave self-paces on counted
// vmcnt(8) (stage k+1 issued, then wait step-k's 8 loads). A stalled wave
// stalls nobody; 10 independent waves/CU cover each other's HBM tails
// (R14-R17: every barrier-coupled variant pinned at ~33-40 us).
// WAR safety (no barrier needed): STAGE(k+1) overwrites buf (k+1)&1 =
// (k-1)&1, whose ds_reads completed (lgkm waits) before step k-1's MFMAs,
// which precede this STAGE in wave program order.
// Bijective XCD swizzle (2560 = 8*320), kh-major; 10 consecutive swz share
// an A-panel (same mBase) -> same-XCD L2 hits.
// -------------------------------------------------------------------------
__global__ __launch_bounds__(64) void gemm_kernel(
    const unsigned short* __restrict__ emb, const unsigned short* __restrict__ bmatT,
    unsigned short* __restrict__ proj)
{
    __shared__ bf16x8 Al[2][4][64];    // 8 KB  (A: [buf][kb][row])
    __shared__ bf16x8 Bl[2][4][64];    // 8 KB

    const int bid  = blockIdx.x;
    const int lane = threadIdx.x;      // 0..63

    // bijective XCD swizzle over 2560 = 8 XCDs x 320; kh-major within swz
    const int swz   = (bid & 7) * 320 + (bid >> 3);
    const int kh    = swz / 1280;           // 0,1
    const int tIdx  = swz - kh * 1280;      // 0..1279
    const int mBase = (tIdx / 10) * 64;
    const int nBase = (tIdx % 10) * 64;
    const int kOff  = kh * KH;

    // staging: lane = row/col; 4 k-oct chunks per operand per step
    const unsigned short* srcA = emb   + (size_t)(mBase + lane) * Dd + kOff;
    const unsigned short* srcB = bmatT + (size_t)(nBase + lane) * Dd + kOff;
    char* ldsA = (char*)&Al[0][0][0] + lane * 16;
    char* ldsB = (char*)&Bl[0][0][0] + lane * 16;

    // compute roles
    const int fr = lane & 15;
    const int kb = lane >> 4;

    f32x4 acc[4][4];
#pragma unroll
    for (int i = 0; i < 4; ++i)
#pragma unroll
        for (int j = 0; j < 4; ++j)
#pragma unroll
            for (int r = 0; r < 4; ++r) acc[i][j][r] = 0.0f;

// 8 loads per STAGE (4 A + 4 B); buf stride 4096 B; chunk j -> kb=j @ +j*1024
#define STAGE(c, off)                                                                          \
    _Pragma("unroll")                                                                          \
    for (int j = 0; j < 4; ++j) {                                                              \
        __builtin_amdgcn_global_load_lds(GPTR(srcA + (off) + j * 8),                           \
                                         LPTR(ldsA + (c) * 4096 + j * 1024), 16, 0, 0);        \
        __builtin_amdgcn_global_load_lds(GPTR(srcB + (off) + j * 8),                           \
                                         LPTR(ldsB + (c) * 4096 + j * 1024), 16, 0, 0);        \
    }

#define COMPUTE(c)                                                                             \
    {                                                                                          \
        bf16x8 a[4], b[4];                                                                     \
        _Pragma("unroll")                                                                      \
        for (int mi = 0; mi < 4; ++mi) a[mi] = Al[c][kb][mi * 16 + fr];                        \
        _Pragma("unroll")                                                                      \
        for (int ni = 0; ni < 4; ++ni) b[ni] = Bl[c][kb][ni * 16 + fr];                        \
        _Pragma("unroll")                                                                      \
        for (int mi = 0; mi < 4; ++mi)                                                         \
            _Pragma("unroll")                                                                  \
            for (int ni = 0; ni < 4; ++ni)                                                     \
                acc[mi][ni] = __builtin_amdgcn_mfma_f32_16x16x32_bf16(a[mi], b[ni],            \
                                                                      acc[mi][ni], 0, 0, 0);   \
    }

// One self-paced K-step: issue next stage, counted-wait own step-k loads
// (8 newer stay in flight), compute. No s_barrier (1 wave owns the LDS).
#define KSTEP(k, cnt)                                                     \
    if ((k) < NST - 1) { STAGE(((k) + 1) & 1, ((k) + 1) * 32); }          \
    asm volatile("s_waitcnt vmcnt(" #cnt ")" ::: "memory");               \
    __builtin_amdgcn_sched_barrier(0);                                    \
    COMPUTE((k) & 1);

    // prologue: step 0 in flight
    STAGE(0, 0);

    KSTEP(0, 8)  KSTEP(1, 8)  KSTEP(2, 8)  KSTEP(3, 8)
    KSTEP(4, 8)  KSTEP(5, 8)  KSTEP(6, 8)  KSTEP(7, 8)
    KSTEP(8, 8)  KSTEP(9, 8)  KSTEP(10, 8) KSTEP(11, 0)

#undef KSTEP
#undef STAGE
#undef COMPUTE

    // C/D layout: col = lane&15, row = (lane>>4)*4 + r   [verified m89/m91]
    unsigned short* projh = proj + (size_t)kh * PBUF;
    const int r0 = mBase + kb * 4;
    const int c0 = nBase + fr;
#pragma unroll
    for (int mi = 0; mi < 4; ++mi)
#pragma unroll
        for (int ni = 0; ni < 4; ++ni)
#pragma unroll
            for (int r = 0; r < 4; ++r)
                projh[(size_t)(r0 + mi * 16 + r) * NPAD + c0 + ni * 16] = f2bf(acc[mi][ni][r]);
}

// -------------------------------------------------------------------------
// Kernel 3: 4 pairs per wave; gathers BOTH K-partials (summed before tanh);
// LDS-tree reduce + wave-parallel softmax. (R13/R17-identical.)
// -------------------------------------------------------------------------
__global__ __launch_bounds__(256) void mlp_kernel(
    const unsigned short* __restrict__ proj,
    const float* __restrict__ b1, const float* __restrict__ w2,
    const float* __restrict__ b2, const int* __restrict__ pair_idx,
    float* __restrict__ out)
{
    __shared__ float red[4][64][17];   // [wave][src lane][16 outputs + pad]

    const int wv   = threadIdx.x >> 6;
    const int wave = blockIdx.x * 4 + wv;                   // 0..8191
    const int lane = threadIdx.x & 63;
    const int wid0 = wave * 4;                              // 4 pairs, same batch
    const int b    = wid0 >> 10;
    const int rbase = b * Ww * NPAD;
    const unsigned short* proj1 = proj + PBUF;

    const int4 piA = *(const int4*)(pair_idx + wid0 * 2);
    const int4 piB = *(const int4*)(pair_idx + wid0 * 2 + 4);
    const int idx[8] = {piA.x, piA.y, piA.z, piA.w, piB.x, piB.y, piB.z, piB.w};

    int off0[4], off1[4];
#pragma unroll
    for (int p = 0; p < 4; ++p) {
        const int i0 = idx[p * 2], i1 = idx[p * 2 + 1];
        off0[p] = (i0 >= 0) ? rbase + i0 * NPAD : ZOFF;
        off1[p] = ((i1 >= 0) ? rbase + i1 * NPAD : ZOFF) + SLOT1;
    }

    unsigned short g0a[4][5], g0b[4][5], g1a[4][5], g1b[4][5];
#pragma unroll
    for (int p = 0; p < 4; ++p)
#pragma unroll
        for (int it = 0; it < 5; ++it) {
            const int j = lane + it * 64;     // j<320; cols [300,320) are zero
            g0a[p][it] = proj [(size_t)off0[p] + j];
            g0b[p][it] = proj1[(size_t)off0[p] + j];
            g1a[p][it] = proj [(size_t)off1[p] + j];
            g1b[p][it] = proj1[(size_t)off1[p] + j];
        }

    float acc[4][4];
#pragma unroll
    for (int p = 0; p < 4; ++p)
#pragma unroll
        for (int c = 0; c < 4; ++c) acc[p][c] = 0.0f;

#pragma unroll
    for (int it = 0; it < 5; ++it) {
        const int j  = lane + it * 64;
        const bool ok = (j < NH);
        const float bj = ok ? b1[j] : 0.0f;
        float4 wv4 = make_float4(0.f, 0.f, 0.f, 0.f);
        if (ok) wv4 = *(const float4*)(w2 + (size_t)j * 4);
#pragma unroll
        for (int p = 0; p < 4; ++p) {
            const float v = bj + (bf2f(g0a[p][it]) + bf2f(g0b[p][it]))
                               + (bf2f(g1a[p][it]) + bf2f(g1b[p][it]));
            const float x = ok ? fast_tanh(v) : 0.0f;
            acc[p][0] = fmaf(x, wv4.x, acc[p][0]);
            acc[p][1] = fmaf(x, wv4.y, acc[p][1]);
            acc[p][2] = fmaf(x, wv4.z, acc[p][2]);
            acc[p][3] = fmaf(x, wv4.w, acc[p][3]);
        }
    }

#pragma unroll
    for (int p = 0; p < 4; ++p)
#pragma unroll
        for (int c = 0; c < 4; ++c)
            red[wv][lane][p * 4 + c] = acc[p][c];
    __syncthreads();

    const int o = lane >> 2;          // output id = p*4+c
    const int g = lane & 3;           // source quarter
    float v = 0.0f;
#pragma unroll
    for (int i = 0; i < 16; ++i)
        v += red[wv][g * 16 + i][o];
    v += __shfl_xor(v, 1, 64);
    v += __shfl_xor(v, 2, 64);

    const int c = o & 3;
    const float l = v + b2[c];
    float mx = fmaxf(l, __shfl_xor(l, 4, 64));
    mx = fmaxf(mx, __shfl_xor(mx, 8, 64));
    const float e = __expf(l - mx);
    float s = e + __shfl_xor(e, 4, 64);
    s += __shfl_xor(s, 8, 64);
    const float r = e * __builtin_amdgcn_rcpf(s);
    if (g == 0)
        out[(size_t)(wid0 + (o >> 2)) * 4 + c] = r;
}

// -------------------------------------------------------------------------
extern "C" void kernel_launch(void* const* d_in, const int* in_sizes, int n_in,
                              void* d_out, int out_size, void* d_ws, size_t ws_size,
                              hipStream_t stream)
{
    const float* h          = (const float*)d_in[0];
    const float* w1         = (const float*)d_in[1];
    const float* b1         = (const float*)d_in[2];
    const float* w2         = (const float*)d_in[3];
    const float* b2         = (const float*)d_in[4];
    const int*   word_start = (const int*)d_in[5];
    const int*   word_len   = (const int*)d_in[6];
    const int*   pair_idx   = (const int*)d_in[7];
    float*       out        = (float*)d_out;

    // workspace layout (all bf16)
    unsigned short* proj  = (unsigned short*)d_ws;                       // 2 partial bufs = 20,974,080 B
    unsigned short* emb   = (unsigned short*)((char*)d_ws + 20975616);   // 12,582,912 B
    unsigned short* bmatT = (unsigned short*)((char*)d_ws + 33558528);   // 983,040 B

    prep_kernel<<<dim3(1024), dim3(256), 0, stream>>>(
        h, w1, word_start, word_len, emb, bmatT, proj);
    gemm_kernel<<<dim3(2560), dim3(64),  0, stream>>>(emb, bmatT, proj);
    mlp_kernel <<<dim3(2048), dim3(256), 0, stream>>>(proj, b1, w2, b2, pair_idx, out);
}

// Round 19
// 53.792 us; speedup vs baseline: 1.8498x; 1.8498x over previous
//
#include <hip/hip_runtime.h>
#include <cstddef>
#include <cstdint>

// Problem constants
#define Bb   32
#define Ss   512
#define Dd   768
#define Ww   256
#define Pp   1024
#define NH   300            // hidden
#define SLOT1 320           // slot-1 column base (128B-aligned)
#define NPAD 640            // padded proj row: [0,300) slot0, [320,620) slot1
#define Mm   (Bb * Ww)      // 8192 words
#define ZROW 8192           // zero row index in proj
#define ZOFF (ZROW * NPAD)  // element offset of zero row

typedef __attribute__((ext_vector_type(8))) short bf16x8;
typedef __attribute__((ext_vector_type(4))) float f32x4;

#define GPTR(p) ((const __attribute__((address_space(1))) void*)(p))
#define LPTR(p) ((__attribute__((address_space(3))) void*)(p))

__device__ __forceinline__ unsigned short f2bf(float x) {
    unsigned u = __builtin_bit_cast(unsigned, x);
    u += 0x7fffu + ((u >> 16) & 1u);          // RNE
    return (unsigned short)(u >> 16);
}
__device__ __forceinline__ float bf2f(unsigned short u) {
    return __builtin_bit_cast(float, (unsigned)u << 16);
}
__device__ __forceinline__ unsigned pk2(float a, float b) {
    return (unsigned)f2bf(a) | ((unsigned)f2bf(b) << 16);
}
__device__ __forceinline__ float fast_tanh(float x) {
    x = fminf(fmaxf(x, -15.0f), 15.0f);
    float e = __expf(2.0f * x);
    return 1.0f - 2.0f * __builtin_amdgcn_rcpf(e + 1.0f);
}

// -------------------------------------------------------------------------
// Kernel 1 (mini-prep), grid-stride 512x256:
//   (a) repack w1 -> BmatT bf16 (SLOT1 layout)
//   (b) zero proj row 8192 (dummy gather row)
// -------------------------------------------------------------------------
__global__ __launch_bounds__(256) void prep_kernel(
    const float* __restrict__ w1, unsigned short* __restrict__ bmatT,
    unsigned short* __restrict__ proj)
{
    const int gid    = blockIdx.x * 256 + threadIdx.x;
    const int stride = 512 * 256;

    for (int u = gid; u < Dd * NPAD; u += stride) {
        const int k = u / NPAD;
        const int n = u - k * NPAD;
        float v = 0.0f;
        if (n < NH)                            v = w1[(size_t)k * NH + n];
        else if (n >= SLOT1 && n < SLOT1 + NH) v = w1[(size_t)(Dd + k) * NH + (n - SLOT1)];
        bmatT[(size_t)n * Dd + k] = f2bf(v);
    }

    if (gid < NPAD / 4)
        *(ushort4*)(proj + ZOFF + gid * 4) = make_ushort4(0, 0, 0, 0);
}

// -------------------------------------------------------------------------
// Kernel 2: FUSED pool + MFMA bf16 GEMM (R13 structure, NO K-split):
//   proj[8192][640] = mean-pool(h) @ Bmat[768][640]
// 320 blocks. Tile 128x128, BK=32, 24 K-steps, 4 waves (2x2), wave 64x64.
// A reg-staged COALESCED (lane -> (row=t>>3, chunk=t&7): 8 x 128B lines per
// wave-load), pooled in-flight (branch-free len), ds_write 8B.
// B via global_load_lds width-16 (linear dest). 2-phase double-buffered LDS.
// Bijective XCD swizzle (320 = 8*40); 5 same-m tiles adjacent on one XCD.
// -------------------------------------------------------------------------
__global__ __launch_bounds__(256) void gemm_kernel(
    const float* __restrict__ h,
    const int* __restrict__ word_start, const int* __restrict__ word_len,
    const unsigned short* __restrict__ bmatT,
    unsigned short* __restrict__ proj)
{
    __shared__ bf16x8 Al[2][4][128];   // 16 KB (pooled A; buf stride 8192 B)
    __shared__ bf16x8 Bl[2][4][128];   // 16 KB

    const int bid = blockIdx.x;
    const int t   = threadIdx.x;

    // bijective XCD swizzle: 320 = 8 XCDs x 40
    const int swz   = (bid & 7) * 40 + (bid >> 3);
    const int mBase = (swz / 5) * 128;
    const int nBase = (swz % 5) * 128;

    // ---- A staging roles (coalesced): row = (t>>3) + p*32, chunk = t&7
    const int srow_s = t >> 3;              // 0..31
    const int chunk  = t & 7;
    const float* hpA[4];
    const float* hpB[4];
#pragma unroll
    for (int p = 0; p < 4; ++p) {
        const int arow = mBase + srow_s + p * 32;      // word id (tile in 1 batch)
        const int s0   = word_start[arow];
        const int len  = word_len[arow];
        const float* base = h + (size_t)(arow >> 8) * (Ss * Dd)
                              + (size_t)s0 * Dd + chunk * 4;
        hpA[p] = base;
        hpB[p] = base + (size_t)(len - 1) * Dd;
    }
    // A LDS dest byte: kb = chunk>>1 (stride 2048), row*16, half 8B; p adds 512
    const int aByte = (chunk >> 1) * 2048 + srow_s * 16 + (chunk & 1) * 8;

    // ---- B staging roles: col = t&127, oct pair {t>>7, t>>7+2}
    const unsigned short* srcB =
        bmatT + (size_t)(nBase + (t & 127)) * Dd + ((t >> 7) << 3);
    char* ldsB = (char*)&Bl[0][0][0] + t * 16;

    // ---- compute roles
    const int lane = t & 63;
    const int w    = t >> 6;
    const int wr   = w >> 1;
    const int wc   = w & 1;
    const int fr   = lane & 15;
    const int kb   = lane >> 4;

    f32x4 acc[4][4];
#pragma unroll
    for (int i = 0; i < 4; ++i)
#pragma unroll
        for (int j = 0; j < 4; ++j)
#pragma unroll
            for (int r = 0; r < 4; ++r) acc[i][j][r] = 0.0f;

    float4 hx[4], hy[4];

#define HLOAD(k0_)                                                        \
    {                                                                     \
        _Pragma("unroll")                                                 \
        for (int p = 0; p < 4; ++p) {                                     \
            hx[p] = *(const float4*)(hpA[p] + (k0_));                     \
            hy[p] = *(const float4*)(hpB[p] + (k0_));                     \
        }                                                                 \
    }

#define POOLW(c)                                                          \
    {                                                                     \
        _Pragma("unroll")                                                 \
        for (int p = 0; p < 4; ++p) {                                     \
            uint2 o;                                                      \
            o.x = pk2((hx[p].x + hy[p].x) * 0.5f,                         \
                      (hx[p].y + hy[p].y) * 0.5f);                        \
            o.y = pk2((hx[p].z + hy[p].z) * 0.5f,                         \
                      (hx[p].w + hy[p].w) * 0.5f);                        \
            *(uint2*)((char*)&Al[0][0][0] + (c) * 8192 + aByte            \
                      + p * (32 * 16)) = o;                               \
        }                                                                 \
    }

#define STAGEB(c, off)                                                                         \
    __builtin_amdgcn_global_load_lds(GPTR(srcB + (off)),      LPTR(ldsB + (c) * 8192),        16, 0, 0); \
    __builtin_amdgcn_global_load_lds(GPTR(srcB + (off) + 16), LPTR(ldsB + (c) * 8192 + 4096), 16, 0, 0)

#define COMPUTE(c)                                                                             \
    {                                                                                          \
        bf16x8 a[4], b[4];                                                                     \
        _Pragma("unroll")                                                                      \
        for (int mi = 0; mi < 4; ++mi) a[mi] = Al[c][kb][wr * 64 + mi * 16 + fr];              \
        _Pragma("unroll")                                                                      \
        for (int ni = 0; ni < 4; ++ni) b[ni] = Bl[c][kb][wc * 64 + ni * 16 + fr];              \
        _Pragma("unroll")                                                                      \
        for (int mi = 0; mi < 4; ++mi)                                                         \
            _Pragma("unroll")                                                                  \
            for (int ni = 0; ni < 4; ++ni)                                                     \
                acc[mi][ni] = __builtin_amdgcn_mfma_f32_16x16x32_bf16(a[mi], b[ni], acc[mi][ni], 0, 0, 0); \
    }

    // prologue: fill buffer 0
    HLOAD(0);
    STAGEB(0, 0);
    POOLW(0);
    __syncthreads();                 // drains vmcnt(0): buf0 (A + B) ready

    int cur = 0;
    for (int k0 = 32; k0 < Dd; k0 += 32) {
        HLOAD(k0);                   // h loads first (oldest in vmcnt queue)
        STAGEB(cur ^ 1, k0);         // B direct-to-LDS, drains at barrier
        COMPUTE(cur);                // MFMA on current buffer meanwhile
        POOLW(cur ^ 1);              // waits only the (older) h loads
        __syncthreads();
        cur ^= 1;
    }
    COMPUTE(cur);
#undef HLOAD
#undef POOLW
#undef STAGEB
#undef COMPUTE

    // C/D layout: col = lane&15, row = (lane>>4)*4 + r   [verified m89/m91]
    const int r0 = mBase + wr * 64 + kb * 4;
    const int c0 = nBase + wc * 64 + fr;
#pragma unroll
    for (int mi = 0; mi < 4; ++mi)
#pragma unroll
        for (int ni = 0; ni < 4; ++ni)
#pragma unroll
            for (int r = 0; r < 4; ++r)
                proj[(size_t)(r0 + mi * 16 + r) * NPAD + c0 + ni * 16] = f2bf(acc[mi][ni][r]);
}

// -------------------------------------------------------------------------
// Kernel 3: 4 pairs per wave, SINGLE-gather (no K-split); LDS-tree reduce +
// wave-parallel softmax. (R9-proven mlp.)
// -------------------------------------------------------------------------
__global__ __launch_bounds__(256) void mlp_kernel(
    const unsigned short* __restrict__ proj,
    const float* __restrict__ b1, const float* __restrict__ w2,
    const float* __restrict__ b2, const int* __restrict__ pair_idx,
    float* __restrict__ out)
{
    __shared__ float red[4][64][17];   // [wave][src lane][16 outputs + pad]

    const int wv   = threadIdx.x >> 6;
    const int wave = blockIdx.x * 4 + wv;                   // 0..8191
    const int lane = threadIdx.x & 63;
    const int wid0 = wave * 4;                              // 4 pairs, same batch
    const int b    = wid0 >> 10;
    const int rbase = b * Ww * NPAD;

    const int4 piA = *(const int4*)(pair_idx + wid0 * 2);
    const int4 piB = *(const int4*)(pair_idx + wid0 * 2 + 4);
    const int idx[8] = {piA.x, piA.y, piA.z, piA.w, piB.x, piB.y, piB.z, piB.w};

    int off0[4], off1[4];
#pragma unroll
    for (int p = 0; p < 4; ++p) {
        const int i0 = idx[p * 2], i1 = idx[p * 2 + 1];
        off0[p] = (i0 >= 0) ? rbase + i0 * NPAD : ZOFF;
        off1[p] = ((i1 >= 0) ? rbase + i1 * NPAD : ZOFF) + SLOT1;
    }

    // issue all 40 gathers up front (coalesced 128B per instr)
    unsigned short g0[4][5], g1[4][5];
#pragma unroll
    for (int p = 0; p < 4; ++p)
#pragma unroll
        for (int it = 0; it < 5; ++it) {
            const int j = lane + it * 64;     // j<320; cols [300,320) are zero
            g0[p][it] = proj[(size_t)off0[p] + j];
            g1[p][it] = proj[(size_t)off1[p] + j];
        }

    float acc[4][4];
#pragma unroll
    for (int p = 0; p < 4; ++p)
#pragma unroll
        for (int c = 0; c < 4; ++c) acc[p][c] = 0.0f;

#pragma unroll
    for (int it = 0; it < 5; ++it) {
        const int j  = lane + it * 64;
        const bool ok = (j < NH);
        const float bj = ok ? b1[j] : 0.0f;
        float4 wv4 = make_float4(0.f, 0.f, 0.f, 0.f);
        if (ok) wv4 = *(const float4*)(w2 + (size_t)j * 4);
#pragma unroll
        for (int p = 0; p < 4; ++p) {
            const float v = bj + bf2f(g0[p][it]) + bf2f(g1[p][it]);
            const float x = ok ? fast_tanh(v) : 0.0f;
            acc[p][0] = fmaf(x, wv4.x, acc[p][0]);
            acc[p][1] = fmaf(x, wv4.y, acc[p][1]);
            acc[p][2] = fmaf(x, wv4.z, acc[p][2]);
            acc[p][3] = fmaf(x, wv4.w, acc[p][3]);
        }
    }

#pragma unroll
    for (int p = 0; p < 4; ++p)
#pragma unroll
        for (int c = 0; c < 4; ++c)
            red[wv][lane][p * 4 + c] = acc[p][c];
    __syncthreads();

    const int o = lane >> 2;          // output id = p*4+c
    const int g = lane & 3;           // source quarter
    float v = 0.0f;
#pragma unroll
    for (int i = 0; i < 16; ++i)
        v += red[wv][g * 16 + i][o];
    v += __shfl_xor(v, 1, 64);
    v += __shfl_xor(v, 2, 64);

    const int c = o & 3;
    const float l = v + b2[c];
    float mx = fmaxf(l, __shfl_xor(l, 4, 64));
    mx = fmaxf(mx, __shfl_xor(mx, 8, 64));
    const float e = __expf(l - mx);
    float s = e + __shfl_xor(e, 4, 64);
    s += __shfl_xor(s, 8, 64);
    const float r = e * __builtin_amdgcn_rcpf(s);
    if (g == 0)
        out[(size_t)(wid0 + (o >> 2)) * 4 + c] = r;
}

// -------------------------------------------------------------------------
extern "C" void kernel_launch(void* const* d_in, const int* in_sizes, int n_in,
                              void* d_out, int out_size, void* d_ws, size_t ws_size,
                              hipStream_t stream)
{
    const float* h          = (const float*)d_in[0];
    const float* w1         = (const float*)d_in[1];
    const float* b1         = (const float*)d_in[2];
    const float* w2         = (const float*)d_in[3];
    const float* b2         = (const float*)d_in[4];
    const int*   word_start = (const int*)d_in[5];
    const int*   word_len   = (const int*)d_in[6];
    const int*   pair_idx   = (const int*)d_in[7];
    float*       out        = (float*)d_out;

    // workspace layout (all bf16)
    unsigned short* proj  = (unsigned short*)d_ws;                       // 8193 x 640 = 10,487,040 B
    unsigned short* bmatT = (unsigned short*)((char*)d_ws + 16777216);   // 983,040 B

    prep_kernel<<<dim3(512),  dim3(256), 0, stream>>>(w1, bmatT, proj);
    gemm_kernel<<<dim3(320),  dim3(256), 0, stream>>>(h, word_start, word_len, bmatT, proj);
    mlp_kernel <<<dim3(2048), dim3(256), 0, stream>>>(proj, b1, w2, b2, pair_idx, out);
}